// Round 6
// baseline (242.619 us; speedup 1.0000x reference)
//
#include <hip/hip_runtime.h>
#include <stdint.h>

// 3-layer GCN, gather-only aggregation off a per-node CSR.
// R21 = R20 + ONE isolated change: DEGREE-SORTED PROCESSING ORDER.
// k_bucket_csr appends an in-bucket counting sort of its 512 nodes by degree
// (64-bin hist + one-wave shuffle scan + cursor scatter -> perm[]). The three
// gather kernels process node = perm[slot]: each wave then spans 64 nodes of
// near-equal degree, so its lockstep neighbor loop runs ~mean-deg iterations
// instead of max-deg-of-64 (Poisson(16): ~16 vs ~29). Self reads/writes stay
// inside the 512-node bucket window (L1/L2-local). Per-node arithmetic and
// neighbor order unchanged -> bit-identical output.
//  k_bin: CHUNK 6400, single-pass (edges packed in registers), pairs loads.
//  k_bucket_csr: 1024 thr, shuffle scan, direct scatter + degree perm.
//  k_agg30: RECOMPUTE form -- gathers 16B float4 (ax,ay,r) from the 3.2MB
//  L2-resident t4 table and rebuilds the 30 h-dims in-register (4 dims/lane,
//  8 lanes/node); FETCH 26MB. fp32 accumulators (R19), 4-unroll (R18).
// Packed edge = (src<<9)|(dst&511), src < 2^18.

#define CAP 9216    // bucket region capacity; mean 8184, sigma 90 -> +11 sigma
#define CHUNK 6400  // edges per k_bin block

__device__ __forceinline__ unsigned short f2bf(float f) {  // RNE, no NaN inputs
    unsigned u = __float_as_uint(f);
    unsigned r = ((u >> 16) & 1u) + 0x7FFFu;
    return (unsigned short)((u + r) >> 16);
}
__device__ __forceinline__ float bf2f(unsigned short h) {
    return __uint_as_float((unsigned)h << 16);
}

// Per-block int64-vs-int32 detect: int64 edge values < 2^18 => all high
// words zero; int32 data at those offsets is src values, ~surely nonzero.
__device__ __forceinline__ int detect64(const unsigned* ei, int* s_nz, int t) {
    unsigned v = ei[2 * (t & 255) + 1];
    if (v != 0) atomicAdd(s_nz, 1);
    __syncthreads();
    return (*s_nz == 0);
}

// Fused binning with local counting sort and coalesced copy-out. 512 thr.
// Edge list read ONCE (pairs via vector loads); packed edges + bucket ids
// held in statically-indexed registers across the scan.
__global__ __launch_bounds__(512) void k_bin(const void* ei, long long E,
                                             int* gcnt, unsigned* binned, int B) {
    __shared__ int cursor[512];
    __shared__ int delta[512];
    __shared__ int wsum[8];
    __shared__ int s_total;
    __shared__ unsigned sv[CHUNK];
    __shared__ unsigned short sb[CHUNK];
    __shared__ int s_nz;
    int t = threadIdx.x, blk = blockIdx.x;
    if (t == 0) s_nz = 0;
    cursor[t] = 0;
    __syncthreads();
    int f = detect64((const unsigned*)ei, &s_nz, t);
    long long s = (long long)blk * CHUNK, e = min(E, s + CHUNK);
    // ---- single global read: pack edges into register slots ----
    unsigned pv[14];
    unsigned short pbk[14];
    if (f) {
        const long long* p = (const long long*)ei;
#pragma unroll
        for (int k = 0; k < 7; k++) {
            long long i = s + 2 * t + (long long)k * 1024;
            if (i + 1 < e) {
                longlong2 sp = *(const longlong2*)(p + i);
                longlong2 dp = *(const longlong2*)(p + E + i);
                pv[2 * k] = ((unsigned)(int)sp.x << 9) | (unsigned)((int)dp.x & 511);
                pbk[2 * k] = (unsigned short)(((int)dp.x) >> 9);
                pv[2 * k + 1] = ((unsigned)(int)sp.y << 9) | (unsigned)((int)dp.y & 511);
                pbk[2 * k + 1] = (unsigned short)(((int)dp.y) >> 9);
            } else if (i < e) {
                int sval = (int)p[i], dv = (int)p[E + i];
                pv[2 * k] = ((unsigned)sval << 9) | (unsigned)(dv & 511);
                pbk[2 * k] = (unsigned short)(dv >> 9);
            }
        }
    } else {
        const int* p = (const int*)ei;
#pragma unroll
        for (int k = 0; k < 7; k++) {
            long long i = s + 2 * t + (long long)k * 1024;
            if (i + 1 < e) {
                int2 sp = *(const int2*)(p + i);
                int2 dp = *(const int2*)(p + E + i);
                pv[2 * k] = ((unsigned)sp.x << 9) | (unsigned)(dp.x & 511);
                pbk[2 * k] = (unsigned short)(dp.x >> 9);
                pv[2 * k + 1] = ((unsigned)sp.y << 9) | (unsigned)(dp.y & 511);
                pbk[2 * k + 1] = (unsigned short)(dp.y >> 9);
            } else if (i < e) {
                int sval = p[i], dv = p[E + i];
                pv[2 * k] = ((unsigned)sval << 9) | (unsigned)(dv & 511);
                pbk[2 * k] = (unsigned short)(dv >> 9);
            }
        }
    }
    // ---- histogram from registers ----
#pragma unroll
    for (int k = 0; k < 14; k++) {
        long long i = s + 2 * t + (long long)(k >> 1) * 1024 + (k & 1);
        if (i < e) atomicAdd(&cursor[pbk[k]], 1);
    }
    __syncthreads();
    // exclusive scan over 512 counts: wave shuffle scan + cross-wave offsets
    int c = cursor[t];
    int lane = t & 63, wid = t >> 6;
    int inc = c;
#pragma unroll
    for (int off = 1; off < 64; off <<= 1) {
        int up = __shfl_up(inc, off, 64);
        if (lane >= off) inc += up;
    }
    if (lane == 63) wsum[wid] = inc;
    __syncthreads();
    int base = 0;
    for (int k = 0; k < wid; k++) base += wsum[k];
    int ex = base + inc - c;
    if (t == 511) s_total = ex + c;
    int claim = c ? atomicAdd(&gcnt[t], c) : 0;
    delta[t] = t * CAP + claim - ex;
    cursor[t] = ex;
    __syncthreads();
    // ---- scatter into LDS from registers ----
#pragma unroll
    for (int k = 0; k < 14; k++) {
        long long i = s + 2 * t + (long long)(k >> 1) * 1024 + (k & 1);
        if (i < e) {
            int pos = atomicAdd(&cursor[pbk[k]], 1);
            sv[pos] = pv[k];
            sb[pos] = pbk[k];
        }
    }
    __syncthreads();
    // linear copy-out (consecutive threads -> consecutive addresses)
    int total = s_total;
    for (int i = t; i < total; i += 512)
        binned[delta[sb[i]] + i] = sv[i];
}

// Per-bucket counting sort by local node, scattering csr DIRECTLY to the
// block-owned global region. 1024 threads; shuffle scan over 512 counters.
// Also iptr2, dinv, p1 = x*dinv. R21: appends an in-bucket counting sort of
// the 512 nodes by degree -> perm[] (degree-uniform waves for the gathers).
__global__ __launch_bounds__(1024) void k_bucket_csr(
        const unsigned* binned, const int* gcnt, const float* x, int2* iptr2,
        float* dinv, float2* p1, int* csr, int* perm, int n) {
    __shared__ int cur[512];
    __shared__ int wsum[16];
    __shared__ int dh[64];
    int t = threadIdx.x, b = blockIdx.x;
    if (t < 512) cur[t] = 0;
    __syncthreads();
    int cnt = gcnt[b];
    const unsigned* bp = binned + (size_t)b * CAP;
    for (int i = t; i < cnt; i += 1024)
        atomicAdd(&cur[bp[i] & 511u], 1);
    __syncthreads();
    int c = (t < 512) ? cur[t] : 0;
    int lane = t & 63, wid = t >> 6;
    int inc = c;
#pragma unroll
    for (int off = 1; off < 64; off <<= 1) {
        int up = __shfl_up(inc, off, 64);
        if (lane >= off) inc += up;
    }
    if (lane == 63) wsum[wid] = inc;
    __syncthreads();
    int base = 0;
    for (int k = 0; k < wid; k++) base += wsum[k];
    int ex = base + inc - c;
    int gbase = b * CAP;
    int node = b * 512 + t;
    if (t < 512) {
        cur[t] = gbase + ex;  // global cursor
        if (node < n) {
            iptr2[node] = make_int2(gbase + ex, gbase + ex + c);
            float dg = (float)(c + 1);  // +1 self loop
            float r = rsqrtf(dg);
            r = r * (1.5f - 0.5f * dg * r * r);  // Newton refine
            dinv[node] = r;
            p1[node] = make_float2(x[2 * node] * r, x[2 * node + 1] * r);
        }
    }
    __syncthreads();
    for (int i = t; i < cnt; i += 1024) {
        unsigned p = bp[i];
        int pos = atomicAdd(&cur[p & 511u], 1);
        csr[pos] = (int)(p >> 9);
    }
    // ---- in-bucket degree sort -> perm (order within a degree bin is
    // arbitrary; per-node arithmetic unaffected) ----
    __syncthreads();
    if (t < 64) dh[t] = 0;
    __syncthreads();
    int d = (t < 512 && node < n) ? min(c, 63) : -1;
    if (d >= 0) atomicAdd(&dh[d], 1);
    __syncthreads();
    if (t < 64) {  // one-wave exclusive scan of the 64 bins
        int v = dh[t];
        int si = v;
#pragma unroll
        for (int off = 1; off < 64; off <<= 1) {
            int up = __shfl_up(si, off, 64);
            if (t >= off) si += up;
        }
        dh[t] = si - v;  // exclusive base; becomes the bin cursor
    }
    __syncthreads();
    if (d >= 0) {
        int pos = atomicAdd(&dh[d], 1);
        perm[b * 512 + pos] = node;
    }
}

// Fused: aggx = A_hat x (dim2, x8 unroll, fp32 pairwise-tree acc);
// t4 = (ax, ay, dinv, 0) -- the 16B generator of this node's h-row.
// Degree-sorted processing: node = perm[slot].
__global__ void k_agg2_l1(const float2* p1, const int2* iptr2, const int* csr,
                          const float* dinv, const int* perm, float4* t4, int n) {
    int slot = blockIdx.x * 256 + threadIdx.x;
    if (slot >= n) return;
    int v = perm[slot];
    float2 a0 = p1[v];
    float dax = a0.x, day = a0.y;
    int2 se = iptr2[v];
    int s = se.x, e = se.y;
    int i = s;
    for (; i + 7 < e; i += 8) {
        int u0 = csr[i], u1 = csr[i + 1], u2 = csr[i + 2], u3 = csr[i + 3];
        int u4 = csr[i + 4], u5 = csr[i + 5], u6 = csr[i + 6], u7 = csr[i + 7];
        float2 q0 = p1[u0], q1 = p1[u1], q2 = p1[u2], q3 = p1[u3];
        float2 q4 = p1[u4], q5 = p1[u5], q6 = p1[u6], q7 = p1[u7];
        dax += ((q0.x + q1.x) + (q2.x + q3.x)) + ((q4.x + q5.x) + (q6.x + q7.x));
        day += ((q0.y + q1.y) + (q2.y + q3.y)) + ((q4.y + q5.y) + (q6.y + q7.y));
    }
    for (; i < e; i++) {
        float2 q = p1[csr[i]];
        dax += q.x; day += q.y;
    }
    float r = dinv[v];
    float ax = dax * r, ay = day * r;
    t4[v] = make_float4(ax, ay, r, 0.f);
}

// Dim-30 aggregation by RECOMPUTE: 8-lane group per node; each lane owns
// dims 4l..4l+3 (W1 columns in registers). Per neighbor: one broadcast 16B
// float4 gather from the 3.2MB t4 table (L2-resident), then
// h_j = relu(ax*W1[j] + ay*W1[30+j] + b1[j]) recomputed in fp32 and
// accumulated scaled via a single fma: acc_j += h_j * r_u. 4 instr/dim.
// Degree-sorted processing: node = perm[group-slot].
__global__ void k_agg30(const float4* t4, const int2* iptr2, const int* csr,
                        const float* W1, const float* b1, const int* perm,
                        uint2* agghu, int n) {
    int t = threadIdx.x;
    int gs = blockIdx.x * 32 + (t >> 3);
    int l = t & 7;
    if (gs >= n) return;
    int g = perm[gs];
    float w0[4], w1[4], bb[4];
#pragma unroll
    for (int k = 0; k < 4; k++) {
        int j = 4 * l + k;
        bool ok = (j < 30);
        w0[k] = ok ? W1[j] : 0.f;
        w1[k] = ok ? W1[30 + j] : 0.f;
        bb[k] = ok ? b1[j] : 0.f;
    }
    float4 qs = t4[g];  // self
    float a0 = fmaxf(fmaf(qs.x, w0[0], fmaf(qs.y, w1[0], bb[0])), 0.f) * qs.z;
    float a1 = fmaxf(fmaf(qs.x, w0[1], fmaf(qs.y, w1[1], bb[1])), 0.f) * qs.z;
    float a2 = fmaxf(fmaf(qs.x, w0[2], fmaf(qs.y, w1[2], bb[2])), 0.f) * qs.z;
    float a3 = fmaxf(fmaf(qs.x, w0[3], fmaf(qs.y, w1[3], bb[3])), 0.f) * qs.z;
#define DIM4(q)                                                                    \
    {                                                                              \
        a0 = fmaf(fmaxf(fmaf(q.x, w0[0], fmaf(q.y, w1[0], bb[0])), 0.f), q.z, a0); \
        a1 = fmaf(fmaxf(fmaf(q.x, w0[1], fmaf(q.y, w1[1], bb[1])), 0.f), q.z, a1); \
        a2 = fmaf(fmaxf(fmaf(q.x, w0[2], fmaf(q.y, w1[2], bb[2])), 0.f), q.z, a2); \
        a3 = fmaf(fmaxf(fmaf(q.x, w0[3], fmaf(q.y, w1[3], bb[3])), 0.f), q.z, a3); \
    }
    int2 se = iptr2[g];
    int s = se.x, e = se.y;
    int i = s;
    for (; i + 3 < e; i += 4) {
        int u0 = csr[i], u1 = csr[i + 1], u2 = csr[i + 2], u3 = csr[i + 3];
        float4 q0 = t4[u0], q1 = t4[u1], q2 = t4[u2], q3 = t4[u3];
        DIM4(q0); DIM4(q1); DIM4(q2); DIM4(q3);
    }
    for (; i < e; i++) {
        float4 q = t4[csr[i]];
        DIM4(q);
    }
#undef DIM4
    float r = qs.z;
    uint2 o;
    o.x = (unsigned)f2bf(a0 * r) | ((unsigned)f2bf(a1 * r) << 16);
    o.y = (unsigned)f2bf(a2 * r) | ((unsigned)f2bf(a3 * r) << 16);
    agghu[(size_t)g * 8 + l] = o;  // pads (cols 30,31) are zero -> stay 0
}

// h2 = relu((Ah1)W2[:30] + (Ax)W2[30:] + b2); p3 = ([h2,x]@W3) * dinv.
// Block stages its 256 bf16 aggh rows through LDS (stride-17 uints).
// Reads t4 for (ax, ay, dinv). Direct (non-permuted) indexing: loop-free.
__global__ void k_layer2(const unsigned short* aggh, const float4* t4,
                         const float* x, const float* W2, const float* W3,
                         const float* b2, float* p3, int n) {
    __shared__ float W2s[32 * 30];
    __shared__ float W3s[32];
    __shared__ float b2s[30];
    __shared__ unsigned hsh[256 * 17];
    int t = threadIdx.x;
    for (int i = t; i < 960; i += 256) W2s[i] = W2[i];
    if (t < 32) W3s[t] = W3[t];
    if (t < 30) b2s[t] = b2[t];
    const unsigned* ag = (const unsigned*)aggh + (size_t)blockIdx.x * 256 * 16;
    int rows = min(256, n - blockIdx.x * 256);
    for (int i = t; i < rows * 16; i += 256) {
        int rr = i >> 4, cc = i & 15;
        hsh[rr * 17 + cc] = ag[i];
    }
    __syncthreads();
    int v = blockIdx.x * 256 + t;
    if (v >= n) return;
    float4 a = t4[v];
    float acc[30];
#pragma unroll
    for (int j = 0; j < 30; j++)
        acc[j] = fmaf(a.x, W2s[30 * 30 + j], fmaf(a.y, W2s[31 * 30 + j], b2s[j]));
#pragma unroll
    for (int kk = 0; kk < 15; kk++) {  // 30 values = 15 uint pairs
        unsigned pr = hsh[t * 17 + kk];
        float h0 = bf2f((unsigned short)(pr & 0xFFFFu));
        float h1v = bf2f((unsigned short)(pr >> 16));
#pragma unroll
        for (int j = 0; j < 30; j++)
            acc[j] = fmaf(h0, W2s[(2 * kk) * 30 + j], acc[j]);
#pragma unroll
        for (int j = 0; j < 30; j++)
            acc[j] = fmaf(h1v, W2s[(2 * kk + 1) * 30 + j], acc[j]);
    }
    float s3 = 0.f;
#pragma unroll
    for (int j = 0; j < 30; j++) s3 = fmaf(fmaxf(acc[j], 0.f), W3s[j], s3);
    s3 = fmaf(x[2 * v], W3s[30], s3);
    s3 = fmaf(x[2 * v + 1], W3s[31], s3);
    p3[v] = s3 * a.z;
}

// out_v = dinv_v * (p3_v + sum p3_u) + b3   (dim 1, x8 unroll, fp32 tree acc)
// Degree-sorted processing: node = perm[slot].
__global__ void k_agg1(const float* p3, const int2* iptr2, const int* csr,
                       const float* dinv, const float* b3, const int* perm,
                       float* out, int n) {
    int slot = blockIdx.x * 256 + threadIdx.x;
    if (slot >= n) return;
    int v = perm[slot];
    float acc = p3[v];
    int2 se = iptr2[v];
    int s = se.x, e = se.y;
    int i = s;
    for (; i + 7 < e; i += 8) {
        int u0 = csr[i], u1 = csr[i + 1], u2 = csr[i + 2], u3 = csr[i + 3];
        int u4 = csr[i + 4], u5 = csr[i + 5], u6 = csr[i + 6], u7 = csr[i + 7];
        float f0 = p3[u0], f1 = p3[u1], f2 = p3[u2], f3 = p3[u3];
        float f4 = p3[u4], f5 = p3[u5], f6 = p3[u6], f7 = p3[u7];
        acc += ((f0 + f1) + (f2 + f3)) + ((f4 + f5) + (f6 + f7));
    }
    for (; i < e; i++) acc += p3[csr[i]];
    out[v] = fmaf(acc, dinv[v], b3[0]);
}

extern "C" void kernel_launch(void* const* d_in, const int* in_sizes, int n_in,
                              void* d_out, int out_size, void* d_ws, size_t ws_size,
                              hipStream_t stream) {
    const float* x  = (const float*)d_in[0];
    const void*  ei = d_in[1];
    const float* W1 = (const float*)d_in[2];
    const float* b1 = (const float*)d_in[3];
    const float* W2 = (const float*)d_in[4];
    const float* b2 = (const float*)d_in[5];
    const float* W3 = (const float*)d_in[6];
    const float* b3 = (const float*)d_in[7];
    float* out = (float*)d_out;
    const int n = in_sizes[0] / 2;
    const long long E = in_sizes[1] / 2;
    const int B = (n + 511) / 512;  // dst buckets of 512 nodes (<=512 buckets)

    char* w = (char*)d_ws;
    auto alloc = [&](size_t b) { void* p = (void*)w; w += (b + 255) & ~(size_t)255; return p; };
    int*            gcnt   = (int*)alloc(512 * 4);
    unsigned*       binned = (unsigned*)alloc((size_t)B * CAP * 4);
    int*            csr    = (int*)alloc((size_t)B * CAP * 4);
    int2*           iptr2  = (int2*)alloc((size_t)n * 8);
    float*          dinv   = (float*)alloc((size_t)n * 4);
    float2*         p1     = (float2*)alloc((size_t)n * 8);
    float4*         t4     = (float4*)alloc((size_t)n * 16);
    unsigned short* aggh   = (unsigned short*)alloc((size_t)n * 32 * 2);
    float*          p3     = (float*)alloc((size_t)n * 4);
    int*            perm   = (int*)alloc((size_t)n * 4);

    int nblocks = (n + 255) / 256;
    int nbin = (int)((E + CHUNK - 1) / CHUNK);

    hipMemsetAsync(gcnt, 0, 512 * 4, stream);
    k_bin<<<nbin, 512, 0, stream>>>(ei, E, gcnt, binned, B);
    k_bucket_csr<<<B, 1024, 0, stream>>>(binned, gcnt, x, iptr2, dinv, p1, csr,
                                         perm, n);
    k_agg2_l1<<<nblocks, 256, 0, stream>>>(p1, iptr2, csr, dinv, perm, t4, n);
    k_agg30<<<(n + 31) / 32, 256, 0, stream>>>(t4, iptr2, csr, W1, b1, perm,
                                               (uint2*)aggh, n);
    k_layer2<<<nblocks, 256, 0, stream>>>(aggh, t4, x, W2, W3, b2, p3, n);
    k_agg1<<<nblocks, 256, 0, stream>>>(p3, iptr2, csr, dinv, b3, perm, out, n);
}

// Round 7
// 211.214 us; speedup vs baseline: 1.1487x; 1.1487x over previous
//
#include <hip/hip_runtime.h>
#include <stdint.h>

// 3-layer GCN, gather-only aggregation off a per-node CSR.
// R22 = R20 (perm REVERTED -- R21's degree-sort scattered all self accesses,
// FETCH 26->58MB, -23us total) + ONE isolated change in k_agg30:
// SHUFFLE-BROADCAST EDGE CHUNKS. The 8 lanes of a node-group now load 8
// DIFFERENT neighbors in parallel (1 coalesced csr load + 1 t4 gather instr
// per 8 edges, was 16 VMEM instrs), then broadcast each neighbor's (ax,ay,r)
// around the group with 3 width-8 __shfl ops (LDS pipe, not TA) while every
// lane accumulates its 4 dims. ~8x fewer VMEM instructions + 8x less load
// address math + divergence granule ceil(deg/8). Neighbor accumulation order
// per dim unchanged -> bit-identical output. Tail lanes masked via r=0.
//  k_bin: CHUNK 6400, single-pass (edges packed in registers), pairs loads.
//  k_bucket_csr: 1024 thr, shuffle scan, direct scatter to owned region.
//  k_agg30: RECOMPUTE form -- 16B float4 (ax,ay,r) gathers from the 3.2MB
//  L2-resident t4 table, 30 h-dims rebuilt in-register (4 dims/lane).
// Packed edge = (src<<9)|(dst&511), src < 2^18.

#define CAP 9216    // bucket region capacity; mean 8184, sigma 90 -> +11 sigma
#define CHUNK 6400  // edges per k_bin block

__device__ __forceinline__ unsigned short f2bf(float f) {  // RNE, no NaN inputs
    unsigned u = __float_as_uint(f);
    unsigned r = ((u >> 16) & 1u) + 0x7FFFu;
    return (unsigned short)((u + r) >> 16);
}
__device__ __forceinline__ float bf2f(unsigned short h) {
    return __uint_as_float((unsigned)h << 16);
}

// Per-block int64-vs-int32 detect: int64 edge values < 2^18 => all high
// words zero; int32 data at those offsets is src values, ~surely nonzero.
__device__ __forceinline__ int detect64(const unsigned* ei, int* s_nz, int t) {
    unsigned v = ei[2 * (t & 255) + 1];
    if (v != 0) atomicAdd(s_nz, 1);
    __syncthreads();
    return (*s_nz == 0);
}

// Fused binning with local counting sort and coalesced copy-out. 512 thr.
// Edge list read ONCE (pairs via vector loads); packed edges + bucket ids
// held in statically-indexed registers across the scan.
__global__ __launch_bounds__(512) void k_bin(const void* ei, long long E,
                                             int* gcnt, unsigned* binned, int B) {
    __shared__ int cursor[512];
    __shared__ int delta[512];
    __shared__ int wsum[8];
    __shared__ int s_total;
    __shared__ unsigned sv[CHUNK];
    __shared__ unsigned short sb[CHUNK];
    __shared__ int s_nz;
    int t = threadIdx.x, blk = blockIdx.x;
    if (t == 0) s_nz = 0;
    cursor[t] = 0;
    __syncthreads();
    int f = detect64((const unsigned*)ei, &s_nz, t);
    long long s = (long long)blk * CHUNK, e = min(E, s + CHUNK);
    // ---- single global read: pack edges into register slots ----
    unsigned pv[14];
    unsigned short pbk[14];
    if (f) {
        const long long* p = (const long long*)ei;
#pragma unroll
        for (int k = 0; k < 7; k++) {
            long long i = s + 2 * t + (long long)k * 1024;
            if (i + 1 < e) {
                longlong2 sp = *(const longlong2*)(p + i);
                longlong2 dp = *(const longlong2*)(p + E + i);
                pv[2 * k] = ((unsigned)(int)sp.x << 9) | (unsigned)((int)dp.x & 511);
                pbk[2 * k] = (unsigned short)(((int)dp.x) >> 9);
                pv[2 * k + 1] = ((unsigned)(int)sp.y << 9) | (unsigned)((int)dp.y & 511);
                pbk[2 * k + 1] = (unsigned short)(((int)dp.y) >> 9);
            } else if (i < e) {
                int sval = (int)p[i], dv = (int)p[E + i];
                pv[2 * k] = ((unsigned)sval << 9) | (unsigned)(dv & 511);
                pbk[2 * k] = (unsigned short)(dv >> 9);
            }
        }
    } else {
        const int* p = (const int*)ei;
#pragma unroll
        for (int k = 0; k < 7; k++) {
            long long i = s + 2 * t + (long long)k * 1024;
            if (i + 1 < e) {
                int2 sp = *(const int2*)(p + i);
                int2 dp = *(const int2*)(p + E + i);
                pv[2 * k] = ((unsigned)sp.x << 9) | (unsigned)(dp.x & 511);
                pbk[2 * k] = (unsigned short)(dp.x >> 9);
                pv[2 * k + 1] = ((unsigned)sp.y << 9) | (unsigned)(dp.y & 511);
                pbk[2 * k + 1] = (unsigned short)(dp.y >> 9);
            } else if (i < e) {
                int sval = p[i], dv = p[E + i];
                pv[2 * k] = ((unsigned)sval << 9) | (unsigned)(dv & 511);
                pbk[2 * k] = (unsigned short)(dv >> 9);
            }
        }
    }
    // ---- histogram from registers ----
#pragma unroll
    for (int k = 0; k < 14; k++) {
        long long i = s + 2 * t + (long long)(k >> 1) * 1024 + (k & 1);
        if (i < e) atomicAdd(&cursor[pbk[k]], 1);
    }
    __syncthreads();
    // exclusive scan over 512 counts: wave shuffle scan + cross-wave offsets
    int c = cursor[t];
    int lane = t & 63, wid = t >> 6;
    int inc = c;
#pragma unroll
    for (int off = 1; off < 64; off <<= 1) {
        int up = __shfl_up(inc, off, 64);
        if (lane >= off) inc += up;
    }
    if (lane == 63) wsum[wid] = inc;
    __syncthreads();
    int base = 0;
    for (int k = 0; k < wid; k++) base += wsum[k];
    int ex = base + inc - c;
    if (t == 511) s_total = ex + c;
    int claim = c ? atomicAdd(&gcnt[t], c) : 0;
    delta[t] = t * CAP + claim - ex;
    cursor[t] = ex;
    __syncthreads();
    // ---- scatter into LDS from registers ----
#pragma unroll
    for (int k = 0; k < 14; k++) {
        long long i = s + 2 * t + (long long)(k >> 1) * 1024 + (k & 1);
        if (i < e) {
            int pos = atomicAdd(&cursor[pbk[k]], 1);
            sv[pos] = pv[k];
            sb[pos] = pbk[k];
        }
    }
    __syncthreads();
    // linear copy-out (consecutive threads -> consecutive addresses)
    int total = s_total;
    for (int i = t; i < total; i += 512)
        binned[delta[sb[i]] + i] = sv[i];
}

// Per-bucket counting sort by local node, scattering csr DIRECTLY to the
// block-owned global region. 1024 threads; shuffle scan over 512 counters.
// Also iptr2, dinv, p1 = x*dinv.
__global__ __launch_bounds__(1024) void k_bucket_csr(
        const unsigned* binned, const int* gcnt, const float* x, int2* iptr2,
        float* dinv, float2* p1, int* csr, int n) {
    __shared__ int cur[512];
    __shared__ int wsum[16];
    int t = threadIdx.x, b = blockIdx.x;
    if (t < 512) cur[t] = 0;
    __syncthreads();
    int cnt = gcnt[b];
    const unsigned* bp = binned + (size_t)b * CAP;
    for (int i = t; i < cnt; i += 1024)
        atomicAdd(&cur[bp[i] & 511u], 1);
    __syncthreads();
    int c = (t < 512) ? cur[t] : 0;
    int lane = t & 63, wid = t >> 6;
    int inc = c;
#pragma unroll
    for (int off = 1; off < 64; off <<= 1) {
        int up = __shfl_up(inc, off, 64);
        if (lane >= off) inc += up;
    }
    if (lane == 63) wsum[wid] = inc;
    __syncthreads();
    int base = 0;
    for (int k = 0; k < wid; k++) base += wsum[k];
    int ex = base + inc - c;
    int gbase = b * CAP;
    if (t < 512) {
        cur[t] = gbase + ex;  // global cursor
        int node = b * 512 + t;
        if (node < n) {
            iptr2[node] = make_int2(gbase + ex, gbase + ex + c);
            float dg = (float)(c + 1);  // +1 self loop
            float r = rsqrtf(dg);
            r = r * (1.5f - 0.5f * dg * r * r);  // Newton refine
            dinv[node] = r;
            p1[node] = make_float2(x[2 * node] * r, x[2 * node + 1] * r);
        }
    }
    __syncthreads();
    for (int i = t; i < cnt; i += 1024) {
        unsigned p = bp[i];
        int pos = atomicAdd(&cur[p & 511u], 1);
        csr[pos] = (int)(p >> 9);
    }
}

// Fused: aggx = A_hat x (dim2, x8 unroll, fp32 pairwise-tree acc);
// t4 = (ax, ay, dinv, 0) -- the 16B generator of this node's h-row.
__global__ void k_agg2_l1(const float2* p1, const int2* iptr2, const int* csr,
                          const float* dinv, float4* t4, int n) {
    int v = blockIdx.x * 256 + threadIdx.x;
    if (v >= n) return;
    float2 a0 = p1[v];
    float dax = a0.x, day = a0.y;
    int2 se = iptr2[v];
    int s = se.x, e = se.y;
    int i = s;
    for (; i + 7 < e; i += 8) {
        int u0 = csr[i], u1 = csr[i + 1], u2 = csr[i + 2], u3 = csr[i + 3];
        int u4 = csr[i + 4], u5 = csr[i + 5], u6 = csr[i + 6], u7 = csr[i + 7];
        float2 q0 = p1[u0], q1 = p1[u1], q2 = p1[u2], q3 = p1[u3];
        float2 q4 = p1[u4], q5 = p1[u5], q6 = p1[u6], q7 = p1[u7];
        dax += ((q0.x + q1.x) + (q2.x + q3.x)) + ((q4.x + q5.x) + (q6.x + q7.x));
        day += ((q0.y + q1.y) + (q2.y + q3.y)) + ((q4.y + q5.y) + (q6.y + q7.y));
    }
    for (; i < e; i++) {
        float2 q = p1[csr[i]];
        dax += q.x; day += q.y;
    }
    float r = dinv[v];
    float ax = dax * r, ay = day * r;
    t4[v] = make_float4(ax, ay, r, 0.f);
}

// Dim-30 aggregation by RECOMPUTE, shuffle-broadcast chunks: 8 lanes/node,
// lane l owns dims 4l..4l+3 (W1 columns in registers). Per 8-edge chunk the
// group loads 8 DIFFERENT neighbors (1 coalesced csr load + 1 t4 gather
// instr), then each neighbor's (ax,ay,r) is broadcast with 3 width-8 shfls;
// every lane accumulates its 4 dims via acc_j = fma(relu(...), r_u, acc_j).
// Tail lanes carry r=0 -> contribution exactly 0. Neighbor order preserved.
__global__ void k_agg30(const float4* t4, const int2* iptr2, const int* csr,
                        const float* W1, const float* b1,
                        uint2* agghu, int n) {
    int t = threadIdx.x;
    int g = blockIdx.x * 32 + (t >> 3);
    int l = t & 7;
    if (g >= n) return;
    float w0[4], w1[4], bb[4];
#pragma unroll
    for (int k = 0; k < 4; k++) {
        int j = 4 * l + k;
        bool ok = (j < 30);
        w0[k] = ok ? W1[j] : 0.f;
        w1[k] = ok ? W1[30 + j] : 0.f;
        bb[k] = ok ? b1[j] : 0.f;
    }
    float4 qs = t4[g];  // self
    float a0 = fmaxf(fmaf(qs.x, w0[0], fmaf(qs.y, w1[0], bb[0])), 0.f) * qs.z;
    float a1 = fmaxf(fmaf(qs.x, w0[1], fmaf(qs.y, w1[1], bb[1])), 0.f) * qs.z;
    float a2 = fmaxf(fmaf(qs.x, w0[2], fmaf(qs.y, w1[2], bb[2])), 0.f) * qs.z;
    float a3 = fmaxf(fmaf(qs.x, w0[3], fmaf(qs.y, w1[3], bb[3])), 0.f) * qs.z;
    int2 se = iptr2[g];
    int s = se.x, e = se.y;
    for (int i = s; i < e; i += 8) {
        int m = e - i;  // valid edges in this chunk (>0)
        int u = (l < m) ? csr[i + l] : 0;
        float4 q = t4[u];
        if (l >= m) { q.x = 0.f; q.y = 0.f; q.z = 0.f; }
#pragma unroll
        for (int k = 0; k < 8; k++) {
            float bx = __shfl(q.x, k, 8);
            float by = __shfl(q.y, k, 8);
            float br = __shfl(q.z, k, 8);
            a0 = fmaf(fmaxf(fmaf(bx, w0[0], fmaf(by, w1[0], bb[0])), 0.f), br, a0);
            a1 = fmaf(fmaxf(fmaf(bx, w0[1], fmaf(by, w1[1], bb[1])), 0.f), br, a1);
            a2 = fmaf(fmaxf(fmaf(bx, w0[2], fmaf(by, w1[2], bb[2])), 0.f), br, a2);
            a3 = fmaf(fmaxf(fmaf(bx, w0[3], fmaf(by, w1[3], bb[3])), 0.f), br, a3);
        }
    }
    float r = qs.z;
    uint2 o;
    o.x = (unsigned)f2bf(a0 * r) | ((unsigned)f2bf(a1 * r) << 16);
    o.y = (unsigned)f2bf(a2 * r) | ((unsigned)f2bf(a3 * r) << 16);
    agghu[(size_t)g * 8 + l] = o;  // pads (cols 30,31) are zero -> stay 0
}

// h2 = relu((Ah1)W2[:30] + (Ax)W2[30:] + b2); p3 = ([h2,x]@W3) * dinv.
// Block stages its 256 bf16 aggh rows through LDS (stride-17 uints).
// Reads t4 for (ax, ay, dinv).
__global__ void k_layer2(const unsigned short* aggh, const float4* t4,
                         const float* x, const float* W2, const float* W3,
                         const float* b2, float* p3, int n) {
    __shared__ float W2s[32 * 30];
    __shared__ float W3s[32];
    __shared__ float b2s[30];
    __shared__ unsigned hsh[256 * 17];
    int t = threadIdx.x;
    for (int i = t; i < 960; i += 256) W2s[i] = W2[i];
    if (t < 32) W3s[t] = W3[t];
    if (t < 30) b2s[t] = b2[t];
    const unsigned* ag = (const unsigned*)aggh + (size_t)blockIdx.x * 256 * 16;
    int rows = min(256, n - blockIdx.x * 256);
    for (int i = t; i < rows * 16; i += 256) {
        int rr = i >> 4, cc = i & 15;
        hsh[rr * 17 + cc] = ag[i];
    }
    __syncthreads();
    int v = blockIdx.x * 256 + t;
    if (v >= n) return;
    float4 a = t4[v];
    float acc[30];
#pragma unroll
    for (int j = 0; j < 30; j++)
        acc[j] = fmaf(a.x, W2s[30 * 30 + j], fmaf(a.y, W2s[31 * 30 + j], b2s[j]));
#pragma unroll
    for (int kk = 0; kk < 15; kk++) {  // 30 values = 15 uint pairs
        unsigned pr = hsh[t * 17 + kk];
        float h0 = bf2f((unsigned short)(pr & 0xFFFFu));
        float h1v = bf2f((unsigned short)(pr >> 16));
#pragma unroll
        for (int j = 0; j < 30; j++)
            acc[j] = fmaf(h0, W2s[(2 * kk) * 30 + j], acc[j]);
#pragma unroll
        for (int j = 0; j < 30; j++)
            acc[j] = fmaf(h1v, W2s[(2 * kk + 1) * 30 + j], acc[j]);
    }
    float s3 = 0.f;
#pragma unroll
    for (int j = 0; j < 30; j++) s3 = fmaf(fmaxf(acc[j], 0.f), W3s[j], s3);
    s3 = fmaf(x[2 * v], W3s[30], s3);
    s3 = fmaf(x[2 * v + 1], W3s[31], s3);
    p3[v] = s3 * a.z;
}

// out_v = dinv_v * (p3_v + sum p3_u) + b3   (dim 1, x8 unroll, fp32 tree acc)
__global__ void k_agg1(const float* p3, const int2* iptr2, const int* csr,
                       const float* dinv, const float* b3, float* out, int n) {
    int v = blockIdx.x * 256 + threadIdx.x;
    if (v >= n) return;
    float acc = p3[v];
    int2 se = iptr2[v];
    int s = se.x, e = se.y;
    int i = s;
    for (; i + 7 < e; i += 8) {
        int u0 = csr[i], u1 = csr[i + 1], u2 = csr[i + 2], u3 = csr[i + 3];
        int u4 = csr[i + 4], u5 = csr[i + 5], u6 = csr[i + 6], u7 = csr[i + 7];
        float f0 = p3[u0], f1 = p3[u1], f2 = p3[u2], f3 = p3[u3];
        float f4 = p3[u4], f5 = p3[u5], f6 = p3[u6], f7 = p3[u7];
        acc += ((f0 + f1) + (f2 + f3)) + ((f4 + f5) + (f6 + f7));
    }
    for (; i < e; i++) acc += p3[csr[i]];
    out[v] = fmaf(acc, dinv[v], b3[0]);
}

extern "C" void kernel_launch(void* const* d_in, const int* in_sizes, int n_in,
                              void* d_out, int out_size, void* d_ws, size_t ws_size,
                              hipStream_t stream) {
    const float* x  = (const float*)d_in[0];
    const void*  ei = d_in[1];
    const float* W1 = (const float*)d_in[2];
    const float* b1 = (const float*)d_in[3];
    const float* W2 = (const float*)d_in[4];
    const float* b2 = (const float*)d_in[5];
    const float* W3 = (const float*)d_in[6];
    const float* b3 = (const float*)d_in[7];
    float* out = (float*)d_out;
    const int n = in_sizes[0] / 2;
    const long long E = in_sizes[1] / 2;
    const int B = (n + 511) / 512;  // dst buckets of 512 nodes (<=512 buckets)

    char* w = (char*)d_ws;
    auto alloc = [&](size_t b) { void* p = (void*)w; w += (b + 255) & ~(size_t)255; return p; };
    int*            gcnt   = (int*)alloc(512 * 4);
    unsigned*       binned = (unsigned*)alloc((size_t)B * CAP * 4);
    int*            csr    = (int*)alloc((size_t)B * CAP * 4);
    int2*           iptr2  = (int2*)alloc((size_t)n * 8);
    float*          dinv   = (float*)alloc((size_t)n * 4);
    float2*         p1     = (float2*)alloc((size_t)n * 8);
    float4*         t4     = (float4*)alloc((size_t)n * 16);
    unsigned short* aggh   = (unsigned short*)alloc((size_t)n * 32 * 2);
    float*          p3     = (float*)alloc((size_t)n * 4);

    int nblocks = (n + 255) / 256;
    int nbin = (int)((E + CHUNK - 1) / CHUNK);

    hipMemsetAsync(gcnt, 0, 512 * 4, stream);
    k_bin<<<nbin, 512, 0, stream>>>(ei, E, gcnt, binned, B);
    k_bucket_csr<<<B, 1024, 0, stream>>>(binned, gcnt, x, iptr2, dinv, p1, csr, n);
    k_agg2_l1<<<nblocks, 256, 0, stream>>>(p1, iptr2, csr, dinv, t4, n);
    k_agg30<<<(n + 31) / 32, 256, 0, stream>>>(t4, iptr2, csr, W1, b1,
                                               (uint2*)aggh, n);
    k_layer2<<<nblocks, 256, 0, stream>>>(aggh, t4, x, W2, W3, b2, p3, n);
    k_agg1<<<nblocks, 256, 0, stream>>>(p3, iptr2, csr, dinv, b3, out, n);
}